// Round 8
// baseline (489.989 us; speedup 1.0000x reference)
//
#include <hip/hip_runtime.h>

typedef __attribute__((ext_vector_type(8))) unsigned short us8;
typedef __attribute__((ext_vector_type(8))) short bf16x8;
typedef __attribute__((ext_vector_type(4))) float f32x4;

#define LMASK 16383
#define SQRT_C 22.627416997969522f
#define LOGIT_MAXV 4.605170185988091f

#define SB __builtin_amdgcn_sched_barrier(0)
#define BAR __builtin_amdgcn_s_barrier()

__device__ __forceinline__ float bf2f(unsigned short u) {
  unsigned int x = ((unsigned int)u) << 16;
  return __builtin_bit_cast(float, x);
}
__device__ __forceinline__ unsigned short f2bf(float f) {
  unsigned int x = __builtin_bit_cast(unsigned int, f);
  x = x + 0x7FFFu + ((x >> 16) & 1u);
  return (unsigned short)(x >> 16);
}
__device__ __forceinline__ void gload16(const void* g, void* lds) {
  __builtin_amdgcn_global_load_lds(
      (const __attribute__((address_space(1))) unsigned int*)g,
      (__attribute__((address_space(3))) unsigned int*)lds, 16, 0, 0);
}

// ---------------- prep kernels ----------------
__global__ void cvt8_k(const float* __restrict__ src, unsigned short* __restrict__ dst, int n8) {
  int idx = blockIdx.x * 256 + threadIdx.x;
  if (idx >= n8) return;
  const float* s = src + (long)idx * 8;
  us8 u;
  #pragma unroll
  for (int e = 0; e < 8; ++e) u[e] = f2bf(s[e]);
  *(us8*)(dst + (long)idx * 8) = u;
}

__global__ void rollcvt_k(const float* __restrict__ x, unsigned short* __restrict__ xb) {
  long e = ((long)blockIdx.x * 256 + threadIdx.x) * 8;
  long row = e >> 9;
  int col = (int)(e & 511);
  long src = ((row >> 14) << 14) | (((row & LMASK) + 64) & LMASK);
  const float* s = x + src * 512 + col;
  us8 u;
  #pragma unroll
  for (int ee = 0; ee < 8; ++ee) u[ee] = f2bf(s[ee]);
  *(us8*)(xb + e) = u;
}

__global__ __launch_bounds__(256) void cpb_k(const float* __restrict__ w1,
    const float* __restrict__ b1, const float* __restrict__ w2,
    float* __restrict__ sig_tbl) {
  __shared__ float hbuf[512];
  const int i = blockIdx.x;
  const int tid = threadIdx.x;
  const float t = (float)(i - 127) * (8.f / 127.f);
  const float sgn = (t < 0.f) ? -1.f : 1.f;
  const float s = sgn * (log2f(fabsf(t) + 1.f) * (1.f / 3.f));
  hbuf[tid]       = fmaxf(s * w1[tid] + b1[tid], 0.f);
  hbuf[tid + 256] = fmaxf(s * w1[tid + 256] + b1[tid + 256], 0.f);
  __syncthreads();
  const int wv = tid >> 6, lane = tid & 63;
  for (int q = 0; q < 4; ++q) {
    const int n = wv * 4 + q;
    float part = 0.f;
    for (int c = lane; c < 512; c += 64) part += hbuf[c] * w2[n * 512 + c];
    #pragma unroll
    for (int o = 1; o < 64; o <<= 1) part += __shfl_xor(part, o);
    if (lane == 0) sig_tbl[i * 16 + n] = 16.f / (1.f + expf(-part));
  }
}

__global__ void qkvbias_k(const float* __restrict__ qb, const float* __restrict__ vb,
                          float* __restrict__ ob) {
  const int n = blockIdx.x * 256 + threadIdx.x;
  float v = 0.f;
  if (n < 512) v = qb[n];
  else if (n >= 1024) v = vb[n - 1024];
  ob[n] = v;
}

// ============ gemm256 body: BM=128, BN=256, BK=32 ============================
// A: 4 LDS slots (32 KB), B: 3 slots (48 KB) -> 80 KB, 2 blocks/CU.
// Issue order per iter: [a(t+3) | laf(t+3)x2 ; b(t+2)x2]; counted waits:
//   AREG0: vmcnt(3)/2/0  AREG1: vmcnt(4)/2/0  (FIFO-derived, tail-exact).
// AREG1: A is f32; pending regs = 2 named sets, loop unrolled x2 (NT even).
template<int NYC, int EPI, int AREG>
__device__ __forceinline__ void gemm256_body(
    const void* __restrict__ Ap, const unsigned short* __restrict__ Bw,
    const float* __restrict__ bias, unsigned short* __restrict__ outb,
    int K, int N) {
  __shared__ unsigned short As[4][4096];   // 4 x 8 KB
  __shared__ unsigned short Bs[3][8192];   // 3 x 16 KB
  const int tid = threadIdx.x;
  const int ww = tid >> 6, l = tid & 63;
  const int wrow = ww >> 2, wcol = ww & 3;
  const int nwg = gridDim.x;
  const int id = blockIdx.x;
  const int lid = (id & 7) * (nwg >> 3) + (id >> 3);
  const int mi = lid / NYC, ni = lid - mi * NYC;
  const int m0 = mi * 128, n0 = ni * 256;
  const int lr = l & 15, lh = l >> 4;
  f32x4 acc[4][4];
  #pragma unroll
  for (int m = 0; m < 4; ++m)
    #pragma unroll
    for (int n = 0; n < 4; ++n) acc[m][n] = (f32x4)0.f;
  const int fsw = (lr >> 1) & 3;
  int aoff[4], boff[4];
  #pragma unroll
  for (int m = 0; m < 4; ++m)
    aoff[m] = (wrow * 64 + m * 16 + lr) * 64 + ((lh ^ fsw) << 4);
  #pragma unroll
  for (int n = 0; n < 4; ++n)
    boff[n] = (wcol * 64 + n * 16 + lr) * 64 + ((lh ^ fsw) << 4);
  const int srow = l >> 2;
  const int schunk = (l & 3) ^ ((srow >> 1) & 3);
  const unsigned short* Ab = (const unsigned short*)Ap;
  const float* Af = (const float*)Ap;
  const int NT = K >> 5;
  const int arow = tid >> 2, aslot = tid & 3;
  const int awoff = arow * 64 + ((aslot ^ ((arow >> 1) & 3)) << 4);
  const char* AsB = (const char*)As;
  const char* BsB = (const char*)Bs;

  auto stage_b = [&](int kt, int bw) {
    #pragma unroll
    for (int rnd = 0; rnd < 2; ++rnd)
      gload16(Bw + (long)(n0 + ww * 32 + rnd * 16 + srow) * K + (kt << 5) + schunk * 8,
              (char*)Bs + bw + ww * 2048 + rnd * 1024);
  };
  auto stage_a = [&](int kt, int aw) {
    gload16(Ab + (long)(m0 + ww * 16 + srow) * K + (kt << 5) + schunk * 8,
            (char*)As + aw + ww * 1024);
  };
  auto laf = [&](int kt, float4& q0, float4& q1) {
    const float* sp = Af + (long)(m0 + arow) * K + (kt << 5) + aslot * 8;
    q0 = *(const float4*)sp;
    q1 = *(const float4*)(sp + 4);
  };
  auto write_af = [&](int aw, const float4& q0, const float4& q1) {
    us8 u;
    u[0] = f2bf(q0.x); u[1] = f2bf(q0.y); u[2] = f2bf(q0.z); u[3] = f2bf(q0.w);
    u[4] = f2bf(q1.x); u[5] = f2bf(q1.y); u[6] = f2bf(q1.z); u[7] = f2bf(q1.w);
    *(us8*)((char*)As + aw + awoff) = u;
  };
  auto compute = [&](int arb, int brb) {
    bf16x8 a[4], b[4];
    #pragma unroll
    for (int m = 0; m < 4; ++m) a[m] = *(const bf16x8*)(AsB + arb + aoff[m]);
    #pragma unroll
    for (int n = 0; n < 4; ++n) b[n] = *(const bf16x8*)(BsB + brb + boff[n]);
    __builtin_amdgcn_s_setprio(1);
    #pragma unroll
    for (int m = 0; m < 4; ++m)
      #pragma unroll
      for (int n = 0; n < 4; ++n)
        acc[m][n] = __builtin_amdgcn_mfma_f32_16x16x32_bf16(a[m], b[n], acc[m][n], 0, 0, 0);
    __builtin_amdgcn_s_setprio(0);
  };

  int arb = 0, awb, brb = 0, bwb;
  float4 pA0, pA1, pB0, pB1;

  if constexpr (AREG == 0) {
    // prologue (order: a0, a1, b0, a2, b1) -> vmcnt(3) at iter 0 forces a0,a1,b0
    stage_a(0, 0);
    stage_a(1, 8192);
    stage_b(0, 0);
    stage_a(2, 16384);
    stage_b(1, 16384);
    awb = 24576; bwb = 32768;
    for (int t = 0; t < NT; ++t) {
      if (t <= NT - 3)      { asm volatile("s_waitcnt vmcnt(3) lgkmcnt(0)" ::: "memory"); }
      else if (t == NT - 2) { asm volatile("s_waitcnt vmcnt(2) lgkmcnt(0)" ::: "memory"); }
      else                  { asm volatile("s_waitcnt vmcnt(0) lgkmcnt(0)" ::: "memory"); }
      SB; BAR; SB;
      if (t + 3 < NT) stage_a(t + 3, awb);
      if (t + 2 < NT) stage_b(t + 2, bwb);
      compute(arb, brb);
      arb += 8192;  if (arb == 32768) arb = 0;
      awb += 8192;  if (awb == 32768) awb = 0;
      brb += 16384; if (brb == 49152) brb = 0;
      bwb += 16384; if (bwb == 49152) bwb = 0;
    }
  } else {
    // prologue: laf0 -> write_af(0); laf1->pA; b0; laf2->pB; b1
    float4 r0, r1;
    laf(0, r0, r1);
    write_af(0, r0, r1);          // auto-waits laf0 only (one-time)
    laf(1, pA0, pA1);
    stage_b(0, 0);
    laf(2, pB0, pB1);
    stage_b(1, 16384);
    awb = 8192; bwb = 32768;      // write_af slot (t+1)%4, stage_b slot (t+2)%3
    for (int t = 0; t < NT; t += 2) {
      // even instance: pend = pA
      {
        if (t <= NT - 3)      { asm volatile("s_waitcnt vmcnt(4) lgkmcnt(0)" ::: "memory"); }
        else if (t == NT - 2) { asm volatile("s_waitcnt vmcnt(2) lgkmcnt(0)" ::: "memory"); }
        else                  { asm volatile("s_waitcnt vmcnt(0) lgkmcnt(0)" ::: "memory"); }
        SB; BAR; SB;
        if (t + 1 < NT) write_af(awb, pA0, pA1);
        if (t + 3 < NT) laf(t + 3, pA0, pA1);
        if (t + 2 < NT) stage_b(t + 2, bwb);
        compute(arb, brb);
        arb += 8192;  if (arb == 32768) arb = 0;
        awb += 8192;  if (awb == 32768) awb = 0;
        brb += 16384; if (brb == 49152) brb = 0;
        bwb += 16384; if (bwb == 49152) bwb = 0;
      }
      // odd instance: pend = pB
      {
        const int u = t + 1;
        if (u <= NT - 3)      { asm volatile("s_waitcnt vmcnt(4) lgkmcnt(0)" ::: "memory"); }
        else if (u == NT - 2) { asm volatile("s_waitcnt vmcnt(2) lgkmcnt(0)" ::: "memory"); }
        else                  { asm volatile("s_waitcnt vmcnt(0) lgkmcnt(0)" ::: "memory"); }
        SB; BAR; SB;
        if (u + 1 < NT) write_af(awb, pB0, pB1);
        if (u + 3 < NT) laf(u + 3, pB0, pB1);
        if (u + 2 < NT) stage_b(u + 2, bwb);
        compute(arb, brb);
        arb += 8192;  if (arb == 32768) arb = 0;
        awb += 8192;  if (awb == 32768) awb = 0;
        brb += 16384; if (brb == 49152) brb = 0;
        bwb += 16384; if (bwb == 49152) bwb = 0;
      }
    }
  }

  float bv[4];
  #pragma unroll
  for (int n = 0; n < 4; ++n) bv[n] = bias[n0 + wcol * 64 + n * 16 + lr];
  #pragma unroll
  for (int m = 0; m < 4; ++m)
    #pragma unroll
    for (int reg = 0; reg < 4; ++reg) {
      const long row = m0 + wrow * 64 + m * 16 + lh * 4 + reg;
      #pragma unroll
      for (int n = 0; n < 4; ++n) {
        const int col = n0 + wcol * 64 + n * 16 + lr;
        float v = acc[m][n][reg] + bv[n];
        if constexpr (EPI == 3) v = v / (1.f + __expf(-v));
        outb[row * (long)N + col] = f2bf(v);
      }
    }
}

// ============ gemmW body: BM=128, BN=512, BK=32, fused RMS epilogue ===========
// A: 6 slots (48 KB) deep pipeline, B: 3 slots (96 KB). 146.5 KB LDS, 1 blk/CU.
// Issue order per iter: [b(t+2)x4, a(t+5)]; waits vmcnt(6)/4/0 (FIFO-derived:
// b(t) forced while a(t+3..5) stay in flight -> A completion deadline 3 iters).
template<int EPI>
__device__ __forceinline__ void gemmW_body(
    const unsigned short* __restrict__ Ab, const unsigned short* __restrict__ Bw,
    const float* __restrict__ bias, const float* __restrict__ resid,
    const float* __restrict__ nw, float* __restrict__ outf, int K) {
  __shared__ unsigned short As[6][4096];    // 6 x 8 KB
  __shared__ unsigned short Bs[3][16384];   // 3 x 32 KB
  __shared__ float rsum[128][4];
  __shared__ float rinv[128];
  const int tid = threadIdx.x;
  const int ww = tid >> 6, l = tid & 63;
  const int wrow = ww >> 2, wcol = ww & 3;
  const int m0 = blockIdx.x * 128;
  const int lr = l & 15, lh = l >> 4;
  f32x4 acc[4][8];
  #pragma unroll
  for (int m = 0; m < 4; ++m)
    #pragma unroll
    for (int n = 0; n < 8; ++n) acc[m][n] = (f32x4)0.f;
  const int fsw = (lr >> 1) & 3;
  int aoff[4], boff[8];
  #pragma unroll
  for (int m = 0; m < 4; ++m)
    aoff[m] = (wrow * 64 + m * 16 + lr) * 64 + ((lh ^ fsw) << 4);
  #pragma unroll
  for (int n = 0; n < 8; ++n)
    boff[n] = (wcol * 128 + n * 16 + lr) * 64 + ((lh ^ fsw) << 4);
  const int srow = l >> 2;
  const int schunk = (l & 3) ^ ((srow >> 1) & 3);
  const int NT = K >> 5;
  const char* AsB = (const char*)As;
  const char* BsB = (const char*)Bs;

  auto stage_b = [&](int kt, int bw) {
    #pragma unroll
    for (int c = 0; c < 4; ++c)
      gload16(Bw + (long)(c * 128 + ww * 16 + srow) * K + (kt << 5) + schunk * 8,
              (char*)Bs + bw + c * 8192 + ww * 1024);
  };
  auto stage_a = [&](int kt, int aw) {
    gload16(Ab + (long)(m0 + ww * 16 + srow) * K + (kt << 5) + schunk * 8,
            (char*)As + aw + ww * 1024);
  };

  // prologue: a0,a1,a2, b0, a3, b1, a4  -> vmcnt(6) at iter 0 forces a0-2,b0
  stage_a(0, 0);
  stage_a(1, 8192);
  stage_a(2, 16384);
  stage_b(0, 0);
  stage_a(3, 24576);
  stage_b(1, 32768);
  stage_a(4, 32768);

  int arb = 0, awb = 40960, brb = 0, bwb = 65536;
  for (int t = 0; t < NT; ++t) {
    if (t <= NT - 5)     { asm volatile("s_waitcnt vmcnt(6) lgkmcnt(0)" ::: "memory"); }
    else if (t < NT - 1) { asm volatile("s_waitcnt vmcnt(4) lgkmcnt(0)" ::: "memory"); }
    else                 { asm volatile("s_waitcnt vmcnt(0) lgkmcnt(0)" ::: "memory"); }
    SB; BAR; SB;
    if (t + 2 < NT) stage_b(t + 2, bwb);
    if (t + 5 < NT) stage_a(t + 5, awb);
    bf16x8 a[4], b[8];
    #pragma unroll
    for (int m = 0; m < 4; ++m) a[m] = *(const bf16x8*)(AsB + arb + aoff[m]);
    #pragma unroll
    for (int n = 0; n < 8; ++n) b[n] = *(const bf16x8*)(BsB + brb + boff[n]);
    __builtin_amdgcn_s_setprio(1);
    #pragma unroll
    for (int m = 0; m < 4; ++m)
      #pragma unroll
      for (int n = 0; n < 8; ++n)
        acc[m][n] = __builtin_amdgcn_mfma_f32_16x16x32_bf16(a[m], b[n], acc[m][n], 0, 0, 0);
    __builtin_amdgcn_s_setprio(0);
    arb += 8192;  if (arb == 49152) arb = 0;
    awb += 8192;  if (awb == 49152) awb = 0;
    brb += 32768; if (brb == 98304) brb = 0;
    bwb += 32768; if (bwb == 98304) bwb = 0;
  }

  float bv[8], nwv[8];
  #pragma unroll
  for (int n = 0; n < 8; ++n) {
    const int col = wcol * 128 + n * 16 + lr;
    bv[n] = bias[col];
    nwv[n] = nw[col];
  }
  float part[4][4];
  #pragma unroll
  for (int m = 0; m < 4; ++m)
    #pragma unroll
    for (int reg = 0; reg < 4; ++reg) {
      float s = 0.f;
      #pragma unroll
      for (int n = 0; n < 8; ++n) {
        float v = acc[m][n][reg] + bv[n];
        s += v * v;
      }
      part[m][reg] = s;
    }
  #pragma unroll
  for (int off = 1; off < 16; off <<= 1)
    #pragma unroll
    for (int m = 0; m < 4; ++m)
      #pragma unroll
      for (int reg = 0; reg < 4; ++reg)
        part[m][reg] += __shfl_xor(part[m][reg], off);
  if (lr == 0) {
    #pragma unroll
    for (int m = 0; m < 4; ++m)
      #pragma unroll
      for (int reg = 0; reg < 4; ++reg)
        rsum[wrow * 64 + m * 16 + lh * 4 + reg][wcol] = part[m][reg];
  }
  __syncthreads();
  if (tid < 128) {
    float s = rsum[tid][0] + rsum[tid][1] + rsum[tid][2] + rsum[tid][3];
    rinv[tid] = SQRT_C * rsqrtf(s * (1.f / 512.f) + 1e-8f);
  }
  __syncthreads();
  #pragma unroll
  for (int m = 0; m < 4; ++m)
    #pragma unroll
    for (int reg = 0; reg < 4; ++reg) {
      const int rl = wrow * 64 + m * 16 + lh * 4 + reg;
      const long grow = m0 + rl;
      const float inv = rinv[rl];
      long orow;
      if constexpr (EPI == 0)
        orow = (grow & ~(long)LMASK) | (((grow & LMASK) + 64) & LMASK);
      else
        orow = grow;
      #pragma unroll
      for (int n = 0; n < 8; ++n) {
        const int col = wcol * 128 + n * 16 + lr;
        float v = acc[m][n][reg] + bv[n];
        outf[orow * 512 + col] = resid[orow * 512 + col] + v * inv * nwv[n];
      }
    }
}

// ---------------- named GEMM kernels ----------------
__global__ __launch_bounds__(512, 4) void qkv_gemm(
    const unsigned short* __restrict__ A, const unsigned short* __restrict__ B,
    const float* __restrict__ bias, unsigned short* __restrict__ C) {
  gemm256_body<6, 2, 0>(A, B, bias, C, 512, 1536);
}
__global__ __launch_bounds__(512, 4) void mlp1_gemm(
    const float* __restrict__ A, const unsigned short* __restrict__ B,
    const float* __restrict__ bias, unsigned short* __restrict__ C) {
  gemm256_body<8, 3, 1>(A, B, bias, C, 512, 2048);
}
__global__ __launch_bounds__(512, 2) void proj_gemm(
    const unsigned short* __restrict__ A, const unsigned short* __restrict__ B,
    const float* __restrict__ bias, const float* __restrict__ resid,
    const float* __restrict__ nw, float* __restrict__ outf) {
  gemmW_body<0>(A, B, bias, resid, nw, outf, 512);
}
__global__ __launch_bounds__(512, 2) void mlp2_gemm(
    const unsigned short* __restrict__ A, const unsigned short* __restrict__ B,
    const float* __restrict__ bias, const float* __restrict__ resid,
    const float* __restrict__ nw, float* __restrict__ outf) {
  gemmW_body<1>(A, B, bias, resid, nw, outf, 2048);
}

// ---------------- attention via MFMA: one block per (head, window) ----------------
__global__ __launch_bounds__(256, 2) void attn_k(const unsigned short* __restrict__ qkv,
    const float* __restrict__ logit_scale, const float* __restrict__ sig_tbl,
    unsigned short* __restrict__ attnout) {
  __shared__ unsigned short qs[128 * 32];
  __shared__ unsigned short ks[128 * 32];
  __shared__ unsigned short vt[32 * 136];
  __shared__ unsigned short ps[128 * 136];
  __shared__ float qinv[128], kinv[128], lbias[256];
  const int h = blockIdx.x, w = blockIdx.y;
  const int tid = threadIdx.x;
  const int wv = tid >> 6, l = tid & 63;
  const int lr = l & 15, quad = l >> 4;

  {
    const int srow = l >> 2;
    const int cs = (l & 3) ^ ((srow >> 1) & 3);
    #pragma unroll
    for (int rnd = 0; rnd < 2; ++rnd) {
      const int row = wv * 32 + rnd * 16 + srow;
      const long gb = (long)(w * 128 + row) * 1536 + h * 32 + cs * 8;
      gload16(qkv + gb, (char*)qs + (wv * 32 + rnd * 16) * 64);
      gload16(qkv + gb + 512, (char*)ks + (wv * 32 + rnd * 16) * 64);
    }
  }
  #pragma unroll
  for (int rnd = 0; rnd < 2; ++rnd) {
    const int j = wv * 32 + rnd * 16 + (l >> 2);
    const int d0 = (l & 3) * 8;
    us8 uv = *(const us8*)(qkv + (long)(w * 128 + j) * 1536 + h * 32 + 1024 + d0);
    #pragma unroll
    for (int e = 0; e < 8; ++e) vt[(d0 + e) * 136 + j] = uv[e];
  }
  if (tid < 255) lbias[tid] = sig_tbl[tid * 16 + h];
  __syncthreads();

  const float scale = __expf(fminf(logit_scale[h], LOGIT_MAXV));
  {
    const int r = tid >> 1, cp = tid & 1;
    const int sw = (r >> 1) & 3;
    float sq = 0.f, sk = 0.f;
    #pragma unroll
    for (int cc = 0; cc < 2; ++cc) {
      const int slot = (cp * 2 + cc) ^ sw;
      us8 uq = *(const us8*)(qs + r * 32 + slot * 8);
      us8 uk = *(const us8*)(ks + r * 32 + slot * 8);
      #pragma unroll
      for (int e = 0; e < 8; ++e) {
        float fq = bf2f(uq[e]), fk = bf2f(uk[e]);
        sq = fmaf(fq, fq, sq);
        sk = fmaf(fk, fk, sk);
      }
    }
    sq += __shfl_xor(sq, 1);
    sk += __shfl_xor(sk, 1);
    qinv[r] = scale / fmaxf(sqrtf(sq), 1e-12f);
    kinv[r] = 1.f / fmaxf(sqrtf(sk), 1e-12f);
  }
  __syncthreads();

  const int fsw = (lr >> 1) & 3;
  bf16x8 aq[2];
  #pragma unroll
  for (int mt = 0; mt < 2; ++mt)
    aq[mt] = *(const bf16x8*)((const char*)qs + (wv * 32 + mt * 16 + lr) * 64 + ((quad ^ fsw) << 4));
  f32x4 s[2][8];
  #pragma unroll
  for (int nt = 0; nt < 8; ++nt) {
    bf16x8 bk = *(const bf16x8*)((const char*)ks + (nt * 16 + lr) * 64 + ((quad ^ fsw) << 4));
    #pragma unroll
    for (int mt = 0; mt < 2; ++mt)
      s[mt][nt] = __builtin_amdgcn_mfma_f32_16x16x32_bf16(aq[mt], bk, (f32x4)0.f, 0, 0, 0);
  }

  float kv8[8];
  #pragma unroll
  for (int nt = 0; nt < 8; ++nt) kv8[nt] = kinv[nt * 16 + lr];
  const bool lastwin = ((w & 127) == 127);
  const bool ihalf = (wv < 2);
  float sum[2][4];
  #pragma unroll
  for (int mt = 0; mt < 2; ++mt) {
    #pragma unroll
    for (int reg = 0; reg < 4; ++reg) {
      const int row = wv * 32 + mt * 16 + quad * 4 + reg;
      const float qv = qinv[row];
      const int bb = row + 127 - lr;
      float m = -1e30f;
      #pragma unroll
      for (int nt = 0; nt < 8; ++nt) {
        float v = s[mt][nt][reg] * qv * kv8[nt] + lbias[bb - nt * 16];
        if (lastwin && (ihalf != (nt < 4))) v -= 100.f;
        s[mt][nt][reg] = v;
        m = fmaxf(m, v);
      }
      m = fmaxf(m, __shfl_xor(m, 1));
      m = fmaxf(m, __shfl_xor(m, 2));
      m = fmaxf(m, __shfl_xor(m, 4));
      m = fmaxf(m, __shfl_xor(m, 8));
      float sm = 0.f;
      #pragma unroll
      for (int nt = 0; nt < 8; ++nt) {
        float p = __expf(s[mt][nt][reg] - m);
        s[mt][nt][reg] = p;
        sm += p;
      }
      sm += __shfl_xor(sm, 1);
      sm += __shfl_xor(sm, 2);
      sm += __shfl_xor(sm, 4);
      sm += __shfl_xor(sm, 8);
      sum[mt][reg] = sm;
      #pragma unroll
      for (int nt = 0; nt < 8; ++nt)
        ps[row * 136 + nt * 16 + lr] = f2bf(s[mt][nt][reg]);
    }
  }
  __syncthreads();

  f32x4 o[2][2];
  #pragma unroll
  for (int mt = 0; mt < 2; ++mt)
    #pragma unroll
    for (int nt = 0; nt < 2; ++nt) o[mt][nt] = (f32x4)0.f;
  #pragma unroll
  for (int kt = 0; kt < 4; ++kt) {
    bf16x8 pa[2], vb[2];
    #pragma unroll
    for (int mt = 0; mt < 2; ++mt)
      pa[mt] = *(const bf16x8*)((const char*)ps + (wv * 32 + mt * 16 + lr) * 272 + (kt * 4 + quad) * 16);
    #pragma unroll
    for (int nt = 0; nt < 2; ++nt)
      vb[nt] = *(const bf16x8*)((const char*)vt + (nt * 16 + lr) * 272 + (kt * 4 + quad) * 16);
    #pragma unroll
    for (int mt = 0; mt < 2; ++mt)
      #pragma unroll
      for (int nt = 0; nt < 2; ++nt)
        o[mt][nt] = __builtin_amdgcn_mfma_f32_16x16x32_bf16(pa[mt], vb[nt], o[mt][nt], 0, 0, 0);
  }
  #pragma unroll
  for (int mt = 0; mt < 2; ++mt) {
    #pragma unroll
    for (int reg = 0; reg < 4; ++reg) {
      const int row = wv * 32 + mt * 16 + quad * 4 + reg;
      const float si = 1.f / sum[mt][reg];
      const long ob = (long)(w * 128 + row) * 512 + h * 32;
      attnout[ob + lr]      = f2bf(o[mt][0][reg] * si);
      attnout[ob + 16 + lr] = f2bf(o[mt][1][reg] * si);
    }
  }
}

// ---------------- launch ----------------
extern "C" void kernel_launch(void* const* d_in, const int* in_sizes, int n_in,
                              void* d_out, int out_size, void* d_ws, size_t ws_size,
                              hipStream_t stream) {
  const float* x       = (const float*)d_in[0];
  const float* qkv_w   = (const float*)d_in[1];
  const float* q_bias  = (const float*)d_in[2];
  const float* v_bias  = (const float*)d_in[3];
  const float* lscale  = (const float*)d_in[4];
  const float* cpb_w1  = (const float*)d_in[5];
  const float* cpb_b1  = (const float*)d_in[6];
  const float* cpb_w2  = (const float*)d_in[7];
  const float* proj_w  = (const float*)d_in[8];
  const float* proj_b  = (const float*)d_in[9];
  const float* norm1_w = (const float*)d_in[10];
  const float* norm2_w = (const float*)d_in[11];
  const float* mlp_w1  = (const float*)d_in[12];
  const float* mlp_b1  = (const float*)d_in[13];
  const float* mlp_w2  = (const float*)d_in[14];
  const float* mlp_b2  = (const float*)d_in[15];
  float* outp = (float*)d_out;
  char* ws = (char*)d_ws;

  unsigned short* w1b     = (unsigned short*)(ws + 0);          // 2 MB   [persist]
  unsigned short* w2b     = (unsigned short*)(ws + 2097152);    // 2 MB   [persist]
  unsigned short* qkv_wb  = (unsigned short*)(ws + 4194304);    // 1.5 MB [persist]
  unsigned short* proj_wb = (unsigned short*)(ws + 5767168);    // 0.5 MB [persist]
  float*          sig_tbl = (float*)(ws + 6291456);             // 16 KB  [persist]
  float*          qkvb    = (float*)(ws + 6311936);             // 6 KB   [persist]
  unsigned short* xb      = (unsigned short*)(ws + 8388608);    // 8..40 MB   [prep->qkv]
  unsigned short* attnout = (unsigned short*)(ws + 8388608);    // 8..40 MB   [attn->proj]
  unsigned short* qkvbuf  = (unsigned short*)(ws + 41943040);   // 40..136 MB [qkv->attn]
  unsigned short* h2      = (unsigned short*)(ws + 33554432);   // 32..160 MB [mlp1->mlp2]

  cvt8_k<<<512, 256, 0, stream>>>(mlp_w1, w1b, 131072);
  cvt8_k<<<512, 256, 0, stream>>>(mlp_w2, w2b, 131072);
  cvt8_k<<<384, 256, 0, stream>>>(qkv_w, qkv_wb, 98304);
  cvt8_k<<<128, 256, 0, stream>>>(proj_w, proj_wb, 32768);
  rollcvt_k<<<8192, 256, 0, stream>>>(x, xb);
  cpb_k<<<255, 256, 0, stream>>>(cpb_w1, cpb_b1, cpb_w2, sig_tbl);
  qkvbias_k<<<6, 256, 0, stream>>>(q_bias, v_bias, qkvb);

  // qkv = xb @ qkv_w^T + qkvb   (M=32768, N=1536, K=512)
  qkv_gemm<<<1536, 512, 0, stream>>>(xb, qkv_wb, qkvb, qkvbuf);
  // attention (MFMA)
  attn_k<<<dim3(16, 256), 256, 0, stream>>>(qkvbuf, lscale, sig_tbl, attnout);
  // proj + rms-norm1 + rolled residual -> outp (f32)
  proj_gemm<<<256, 512, 0, stream>>>(attnout, proj_wb, proj_b, x, norm1_w, outp);
  // h2 = silu(outp @ w1^T + b1)  (M=32768, N=2048, K=512), f32 A deep reg-stage
  mlp1_gemm<<<2048, 512, 0, stream>>>(outp, w1b, mlp_b1, h2);
  // mlp2 + rms-norm2 + residual (in place on outp)
  mlp2_gemm<<<256, 512, 0, stream>>>(h2, w2b, mlp_b2, outp, norm2_w, outp);
}